// Round 9
// baseline (383.379 us; speedup 1.0000x reference)
//
#include <hip/hip_runtime.h>
#include <cstdint>
#include <cstddef>

#define BB 32
#define NN 1024
#define CIN 128
#define FF 64
#define NOUT 10
#define CAP 128
#define EPSV 1e-5f

// Register-tiled GEMM: 64 rows x 64 cols per block, 4x4 outputs/thread, k chunked by 32.
// LDS: W-chunk [32][64] (8 KB) + transposed x-chunk xT[32][64] (8 KB) + 64 row-scales.
// Per k: 2x ds_read_b128 (both broadcast/2-way, conflict-free) + 16 FMAs -> 2 B LDS/output
// (was 5 B/output in the 1x4 shape). Scale applied at staging (reference order).
template<int K, bool SCALED>
__device__ __forceinline__ void gemm_tile(int row0, const float* __restrict__ Xin,
                                          const float* __restrict__ W,
                                          const float* __restrict__ y,
                                          const float* __restrict__ nm,
                                          float* __restrict__ T,
                                          float* smem, int tid) {
    float4* sW  = (float4*)smem;           // 512 float4
    float4* sXT = sW + 512;                // 512 float4
    float*  sSc = (float*)(sXT + 512);     // 64 floats
    if (SCALED && tid < 64)
        sSc[tid] = tanhf(y[row0 + tid]) * nm[row0 + tid];
    int c = tid & 15, rg = tid >> 4;
    float4 acc0 = {0.f,0.f,0.f,0.f}, acc1 = acc0, acc2 = acc0, acc3 = acc0;
    const int KF4 = K / 4;                 // row stride of Xin in float4
    const float4* X4 = (const float4*)Xin;
    const float4* W4 = (const float4*)W;
#pragma unroll
    for (int kc = 0; kc < K / 32; ++kc) {
        __syncthreads();   // prev-chunk reads done; sSc ready on first pass
        // stage W chunk (coalesced copy)
        for (int t2 = tid; t2 < 512; t2 += 256)
            sW[t2] = W4[kc * 512 + t2];
        // stage xT chunk: sXT[k][row] = Xin[row0+row][kc*32+k] * sc[row]
        for (int t2 = tid; t2 < 512; t2 += 256) {
            int row = t2 >> 3, kk4 = t2 & 7;
            float4 v = X4[(size_t)(row0 + row) * KF4 + kc * 8 + kk4];
            float s = SCALED ? sSc[row] : 1.0f;
            int kb = kk4 * 4;
            float* dst = (float*)sXT;
            dst[(kb + 0) * 64 + row] = v.x * s;
            dst[(kb + 1) * 64 + row] = v.y * s;
            dst[(kb + 2) * 64 + row] = v.z * s;
            dst[(kb + 3) * 64 + row] = v.w * s;
        }
        __syncthreads();
#pragma unroll 8
        for (int k = 0; k < 32; ++k) {
            float4 wv = sW[k * 16 + c];
            float4 xv = sXT[k * 16 + rg];
            acc0.x += xv.x * wv.x; acc0.y += xv.x * wv.y; acc0.z += xv.x * wv.z; acc0.w += xv.x * wv.w;
            acc1.x += xv.y * wv.x; acc1.y += xv.y * wv.y; acc1.z += xv.y * wv.z; acc1.w += xv.y * wv.w;
            acc2.x += xv.z * wv.x; acc2.y += xv.z * wv.y; acc2.z += xv.z * wv.z; acc2.w += xv.z * wv.w;
            acc3.x += xv.w * wv.x; acc3.y += xv.w * wv.y; acc3.z += xv.w * wv.z; acc3.w += xv.w * wv.w;
        }
    }
    int rbase = row0 + 4 * rg;
    *(float4*)&T[(size_t)(rbase + 0) * 64 + 4 * c] = acc0;
    *(float4*)&T[(size_t)(rbase + 1) * 64 + 4 * c] = acc1;
    *(float4*)&T[(size_t)(rbase + 2) * 64 + 4 * c] = acc2;
    *(float4*)&T[(size_t)(rbase + 3) * 64 + 4 * c] = acc3;
}

// ---------------- fused front: [0,8192) = CSR build, [8192,8704) = x@W0 gemm ----------------
// 16.3 KB static LDS -> CSR occupancy 32 waves/CU (was 20 with the 32 KB Wl).
__global__ __launch_bounds__(256) void k_front(const float* __restrict__ A,
                                               const float* __restrict__ x,
                                               const float* __restrict__ W0,
                                               unsigned short* __restrict__ adj,
                                               int* __restrict__ cnt,
                                               float* __restrict__ c1,
                                               float* __restrict__ c2,
                                               float* __restrict__ T) {
    __shared__ __align__(16) float smem[512 * 4 * 2 + 64];
    int tid = threadIdx.x;
    int wave = tid >> 6, lane = tid & 63;
    if (blockIdx.x >= 8192) {
        int gid = blockIdx.x - 8192;        // 8192%8==0 -> XCD gid%8 == b%8, matches spmm
        int b = gid & 31;
        int cch = gid >> 5;                 // chunk in [0,16)
        int row0 = (b << 10) + cch * 64;
        gemm_tile<CIN, false>(row0, x, W0, nullptr, nullptr, T, smem, tid);
    } else {
        // ---- CSR build: wave per row, ballot prefix-compaction (ascending j) ----
        unsigned short* adjs = ((unsigned short*)smem) + wave * CAP;   // 256 B per wave
        int r = blockIdx.x * 4 + wave;                 // global row in [0, B*N)
        const float4* Arow = (const float4*)(A + (size_t)r * NN);
        float4 v0 = Arow[lane];
        float4 v1 = Arow[64 + lane];
        float4 v2 = Arow[128 + lane];
        float4 v3 = Arow[192 + lane];
        int c = 0;
        unsigned long long lt = (lane == 0) ? 0ULL : ((1ULL << lane) - 1ULL);
        float4 vv[4] = {v0, v1, v2, v3};
#pragma unroll
        for (int it = 0; it < 4; ++it) {
            float4 v = vv[it];
            int j0 = it * 256 + lane * 4;
            unsigned long long m0 = __ballot(v.x != 0.f);
            unsigned long long m1 = __ballot(v.y != 0.f);
            unsigned long long m2 = __ballot(v.z != 0.f);
            unsigned long long m3 = __ballot(v.w != 0.f);
            int before = __popcll(m0 & lt) + __popcll(m1 & lt) +
                         __popcll(m2 & lt) + __popcll(m3 & lt);
            int p = c + before;
            if (v.x != 0.f) { if (p < CAP) adjs[p] = (unsigned short)(j0 + 0); ++p; }
            if (v.y != 0.f) { if (p < CAP) adjs[p] = (unsigned short)(j0 + 1); ++p; }
            if (v.z != 0.f) { if (p < CAP) adjs[p] = (unsigned short)(j0 + 2); ++p; }
            if (v.w != 0.f) { if (p < CAP) adjs[p] = (unsigned short)(j0 + 3); ++p; }
            c += __popcll(m0) + __popcll(m1) + __popcll(m2) + __popcll(m3);
        }
        int cc = (c > CAP) ? CAP : c;
        // coalesced flush: one u32 per lane covers 2 entries
        uint32_t* dst = (uint32_t*)(adj + (size_t)r * CAP);
        if (lane * 2 < cc) dst[lane] = ((const uint32_t*)adjs)[lane];
        if (lane == 0) {
            cnt[r] = cc;
            float D = 1.0f / sqrtf((float)c + 1.0f + EPSV);
            c1[r] = D;
            c2[r] = D * D;
        }
    }
}

// ---------------- fused mid: [0,8192) = deg, [8192,8704) = gemm64 (scaled) ----------------
__global__ __launch_bounds__(256) void k_mid(const unsigned short* __restrict__ adj,
                                             const int* __restrict__ cnt,
                                             const float* __restrict__ nm,
                                             float* __restrict__ c1, float* __restrict__ c2,
                                             const float* __restrict__ Xin,
                                             const float* __restrict__ W,
                                             const float* __restrict__ y,
                                             float* __restrict__ T) {
    __shared__ __align__(16) float smem[512 * 4 * 2 + 64];
    int tid = threadIdx.x;
    if (blockIdx.x >= 8192) {
        int gid = blockIdx.x - 8192;
        int b = gid & 31;                   // XCD matches spmm reader
        int cch = gid >> 5;
        int row0 = (b << 10) + cch * 64;
        gemm_tile<FF, true>(row0, Xin, W, y, nm, T, smem, tid);
    } else {
        // ---- masked degree, wave per row (nm entries are 0/1 -> order-exact) ----
        int wave = tid >> 6, lane = tid & 63;
        int r = blockIdx.x * 4 + wave;
        int b = r >> 10;
        const unsigned short* arow = adj + (size_t)r * CAP;
        const float* nmb = nm + (b << 10);
        int n = cnt[r];
        float s = 0.f;
        if (lane < n)      s  = nmb[arow[lane]];
        if (lane + 64 < n) s += nmb[arow[lane + 64]];
        for (int sh = 32; sh; sh >>= 1) s += __shfl_xor(s, sh, 64);
        if (lane == 0) {
            float m = nm[r];
            float D = 1.0f / sqrtf(m * s + 1.0f + EPSV);
            c1[r] = m * D;
            c2[r] = D * D;
        }
    }
}

// ---------------- SpMM + self + bias + relu (+ pool score OR fused global max) ----------------
__global__ __launch_bounds__(256) void k_spmm(const unsigned short* __restrict__ adj,
                                              const int* __restrict__ cnt,
                                              const float* __restrict__ c1,
                                              const float* __restrict__ c2,
                                              const float* __restrict__ T,
                                              const float* __restrict__ bias,
                                              float* __restrict__ X,
                                              const float* __restrict__ p,
                                              float* __restrict__ y,
                                              float* __restrict__ gmax) {
    __shared__ __align__(16) float c1s[NN];
    __shared__ float red[4][64];
    int b   = blockIdx.x & 31;            // graph
    int cch = blockIdx.x >> 5;            // chunk in [0,64)
    int tid = threadIdx.x;
    ((float4*)c1s)[tid] = ((const float4*)(c1 + (b << 10)))[tid];
    __syncthreads();
    int wave = tid >> 6, lane = tid & 63;
    int r0 = (b << 10) + cch * 16 + wave * 4;
    const float* Tb = T + ((size_t)(b << 10) << 6);
    float bv = bias[lane];
    float pv = 0.f, ppinv = 0.f;
    if (p != nullptr) {
        pv = p[lane];
        float pp = pv * pv;
        for (int s = 32; s; s >>= 1) pp += __shfl_xor(pp, s, 64);
        ppinv = 1.0f / sqrtf(pp);
    }
    float vmax = 0.f;
#pragma unroll
    for (int rr = 0; rr < 4; ++rr) {
        int r = r0 + rr;
        const unsigned short* arow = adj + (size_t)r * CAP;
        int n = cnt[r];
        float acc0 = 0.f, acc1 = 0.f, acc2 = 0.f, acc3 = 0.f;
        int t = 0;
        for (; t + 4 <= n; t += 4) {
            ushort4 j4 = *(const ushort4*)(arow + t);
            acc0 += c1s[j4.x] * Tb[((int)j4.x << 6) + lane];
            acc1 += c1s[j4.y] * Tb[((int)j4.y << 6) + lane];
            acc2 += c1s[j4.z] * Tb[((int)j4.z << 6) + lane];
            acc3 += c1s[j4.w] * Tb[((int)j4.w << 6) + lane];
        }
        for (; t < n; ++t) {
            int j = arow[t];
            acc0 += c1s[j] * Tb[(j << 6) + lane];
        }
        float acc = (acc0 + acc1) + (acc2 + acc3);
        int rl = r & 1023;
        float o = c1s[rl] * acc + c2[r] * T[((size_t)r << 6) + lane] + bv;
        o = fmaxf(o, 0.f);
        if (X != nullptr) X[((size_t)r << 6) + lane] = o;
        if (p != nullptr) {
            float a = o * pv;
            for (int s = 32; s; s >>= 1) a += __shfl_xor(a, s, 64);
            if (lane == 0) y[r] = a * ppinv;
        }
        vmax = fmaxf(vmax, o);
    }
    if (gmax != nullptr) {
        red[wave][lane] = vmax;
        __syncthreads();
        if (wave == 0) {
            float m = fmaxf(fmaxf(red[0][lane], red[1][lane]),
                            fmaxf(red[2][lane], red[3][lane]));
            atomicMax((int*)&gmax[(b << 6) + lane], __float_as_int(m));
        }
    }
}

// ---------------- pool ranking: stable-argsort semantics, 16 blocks/graph ----------------
__global__ __launch_bounds__(256) void k_rank(const float* __restrict__ y,
                                              const float* __restrict__ maskSrc,
                                              const int* __restrict__ nsrc,
                                              float* __restrict__ nmOut,
                                              int* __restrict__ ncur) {
    __shared__ __align__(16) float yv[NN];
    int b = blockIdx.x >> 4;       // 16 blocks per graph
    int sub = blockIdx.x & 15;
    int tid = threadIdx.x;
    const float INF = __builtin_inff();
    {
        float4 v = ((const float4*)(y + (b << 10)))[tid];
        float4 m = ((const float4*)(maskSrc + (b << 10)))[tid];
        v.x = (m.x > 0.f) ? v.x : INF;
        v.y = (m.y > 0.f) ? v.y : INF;
        v.z = (m.z > 0.f) ? v.z : INF;
        v.w = (m.w > 0.f) ? v.w : INF;
        ((float4*)yv)[tid] = v;
    }
    int n = nsrc[b];
    const float RM = (float)(1.0 - 0.8);   // 0.2f, matches jax f32 semantics
    int nrem = (int)((float)n * RM);
    if (sub == 0 && tid == 0) ncur[b] = n - nrem;
    __syncthreads();
    int i = (sub << 6) + (tid >> 2);       // 64 nodes per block, 4 threads per node
    int q = tid & 3;                       // quarter of the j-range
    float yi = yv[i];
    int rank = 0;
    if (yi < INF) {
        const float4* jbase = (const float4*)yv + (q << 6);
        int j0 = q << 8;
#pragma unroll 8
        for (int t = 0; t < 64; ++t) {
            float4 a = jbase[t];
            int j = j0 + t * 4;
            rank += (a.x < yi || (a.x == yi && j     < i)) ? 1 : 0;
            rank += (a.y < yi || (a.y == yi && j + 1 < i)) ? 1 : 0;
            rank += (a.z < yi || (a.z == yi && j + 2 < i)) ? 1 : 0;
            rank += (a.w < yi || (a.w == yi && j + 3 < i)) ? 1 : 0;
        }
    }
    rank += __shfl_xor(rank, 1, 64);
    rank += __shfl_xor(rank, 2, 64);
    if (q == 0) {
        float nmv = (yi < INF && rank >= nrem) ? 1.f : 0.f;
        nmOut[(b << 10) + i] = nmv;
    }
}

// ---------------- final fc from the fused global-max buffer ----------------
__global__ __launch_bounds__(64) void k_fc(const float* __restrict__ gmax,
                                           const float* __restrict__ Wfc,
                                           const float* __restrict__ bfc,
                                           float* __restrict__ out) {
    __shared__ float gl[64];
    int b = blockIdx.x, lane = threadIdx.x;
    gl[lane] = gmax[(b << 6) + lane];
    __syncthreads();
    if (lane < NOUT) {
        float acc = bfc[lane];
        for (int k = 0; k < 64; ++k) acc += gl[k] * Wfc[k * NOUT + lane];
        out[b * NOUT + lane] = acc;
    }
}

extern "C" void kernel_launch(void* const* d_in, const int* in_sizes, int n_in,
                              void* d_out, int out_size, void* d_ws, size_t ws_size,
                              hipStream_t stream) {
    const float* x    = (const float*)d_in[0];
    const float* A    = (const float*)d_in[1];
    const float* mask = (const float*)d_in[2];
    const int*   Nn   = (const int*)d_in[3];
    const float* W0   = (const float*)d_in[4];
    const float* b0   = (const float*)d_in[5];
    const float* W1   = (const float*)d_in[6];
    const float* b1   = (const float*)d_in[7];
    const float* W2   = (const float*)d_in[8];
    const float* b2   = (const float*)d_in[9];
    const float* p0   = (const float*)d_in[10];
    const float* p1   = (const float*)d_in[11];
    const float* Wfc  = (const float*)d_in[12];
    const float* bfc  = (const float*)d_in[13];
    float* out = (float*)d_out;

    char* ws = (char*)d_ws;
    size_t off = 0;
    auto alloc = [&](size_t bytes) -> void* {
        void* p = ws + off;
        off = (off + bytes + 255) & ~(size_t)255;
        return p;
    };
    unsigned short* adj = (unsigned short*)alloc((size_t)BB * NN * CAP * 2);
    int*   cnt  = (int*)  alloc((size_t)BB * NN * 4);
    float* X    = (float*)alloc((size_t)BB * NN * 64 * 4);
    float* T    = (float*)alloc((size_t)BB * NN * 64 * 4);
    float* c1   = (float*)alloc((size_t)BB * NN * 4);
    float* c2   = (float*)alloc((size_t)BB * NN * 4);
    float* y    = (float*)alloc((size_t)BB * NN * 4);
    float* nm0  = (float*)alloc((size_t)BB * NN * 4);
    float* nm1  = (float*)alloc((size_t)BB * NN * 4);
    int*   nc0  = (int*)  alloc((size_t)BB * 4);
    int*   nc1  = (int*)  alloc((size_t)BB * 4);
    float* gmax = (float*)alloc((size_t)BB * 64 * 4);

    // zero the fused-max buffer (ws is poisoned 0xAA before every call)
    hipMemsetAsync(gmax, 0, (size_t)BB * 64 * 4, stream);
    // 1) fused: CSR build (8192 blocks) + x@W0 register-tiled gemm (512 blocks)
    k_front<<<8192 + 512, 256, 0, stream>>>(A, x, W0, adj, cnt, c1, c2, T);
    // 2) layer 1 SpMM (+ pool-1 score)
    k_spmm<<<2048, 256, 0, stream>>>(adj, cnt, c1, c2, T, b0, X, p0, y, nullptr);
    // pool 1
    k_rank<<<BB * 16, 256, 0, stream>>>(y, mask, Nn, nm0, nc0);
    // 3) layer 2: fused deg (first) + register-tiled gemm64
    k_mid<<<8192 + 512, 256, 0, stream>>>(adj, cnt, nm0, c1, c2, X, W1, y, T);
    k_spmm<<<2048, 256, 0, stream>>>(adj, cnt, c1, c2, T, b1, X, p1, y, nullptr);
    // pool 2 (double-buffered mask)
    k_rank<<<BB * 16, 256, 0, stream>>>(y, nm0, nc0, nm1, nc1);
    // 4) layer 3: fused deg (first) + gemm64; spmm fuses global max (no X write)
    k_mid<<<8192 + 512, 256, 0, stream>>>(adj, cnt, nm1, c1, c2, X, W2, y, T);
    k_spmm<<<2048, 256, 0, stream>>>(adj, cnt, c1, c2, T, b2, nullptr, nullptr, nullptr, gmax);
    // 5) fc from gmax
    k_fc<<<BB, 64, 0, stream>>>(gmax, Wfc, bfc, out);
}

// Round 10
// 372.516 us; speedup vs baseline: 1.0292x; 1.0292x over previous
//
#include <hip/hip_runtime.h>
#include <cstdint>
#include <cstddef>

#define BB 32
#define NN 1024
#define CIN 128
#define FF 64
#define NOUT 10
#define CAP 128
#define EPSV 1e-5f

// ---------------- fused front: [0,8192) = CSR build, [8192,10240) = x@W0 gemm ----------------
// CSR first (latency-bound A-scan starts at t=0). W0 staged in TWO 16 KB k-chunks
// (was one 32 KB chunk in R8): halves LDS -> 32 waves/CU for the latency-bound scan
// (was 20). Gemm keeps R8's proven 16-rows/block shape. Compacted CSR row staged in
// LDS (aliases Wl), flushed as one coalesced u32 store per lane.
__global__ __launch_bounds__(256) void k_front(const float* __restrict__ A,
                                               const float* __restrict__ x,
                                               const float* __restrict__ W0,
                                               unsigned short* __restrict__ adj,
                                               int* __restrict__ cnt,
                                               float* __restrict__ c1,
                                               float* __restrict__ c2,
                                               float* __restrict__ T) {
    __shared__ __align__(16) float Wl[64 * 64];    // 16 KB
    int tid = threadIdx.x;
    int wave = tid >> 6, lane = tid & 63;
    if (blockIdx.x >= 8192) {
        // ---- gemm: T[row, f] = sum_k x[row,k] * W0[k,f], 16 rows per block ----
        int gid = blockIdx.x - 8192;        // 8192%8==0 -> XCD gid%8 == b%8, matches spmm
        int b = gid & 31;
        int cch = gid >> 5;                 // chunk in [0,64)
        int row0 = (b << 10) + cch * 16;
        int rsub = lane >> 4, f0 = (lane & 15) * 4;
        int r = row0 + wave * 4 + rsub;
        const float4* xr = (const float4*)(x + (size_t)r * CIN);
        float4 acc = {0.f, 0.f, 0.f, 0.f};
#pragma unroll
        for (int kc = 0; kc < 2; ++kc) {    // two 64-k chunks of W0
            if (kc) __syncthreads();        // drain prev-chunk readers
            for (int t = tid; t < 64 * 16; t += 256)
                ((float4*)Wl)[t] = ((const float4*)W0)[kc * 1024 + t];
            __syncthreads();
#pragma unroll 4
            for (int k4 = 0; k4 < 16; ++k4) {
                float4 xv = xr[kc * 16 + k4];             // broadcast within 16-lane group
                float4 w0 = *(const float4*)&Wl[(k4 * 4 + 0) * 64 + f0];
                float4 w1 = *(const float4*)&Wl[(k4 * 4 + 1) * 64 + f0];
                float4 w2 = *(const float4*)&Wl[(k4 * 4 + 2) * 64 + f0];
                float4 w3 = *(const float4*)&Wl[(k4 * 4 + 3) * 64 + f0];
                acc.x += xv.x * w0.x; acc.y += xv.x * w0.y; acc.z += xv.x * w0.z; acc.w += xv.x * w0.w;
                acc.x += xv.y * w1.x; acc.y += xv.y * w1.y; acc.z += xv.y * w1.z; acc.w += xv.y * w1.w;
                acc.x += xv.z * w2.x; acc.y += xv.z * w2.y; acc.z += xv.z * w2.z; acc.w += xv.z * w2.w;
                acc.x += xv.w * w3.x; acc.y += xv.w * w3.y; acc.z += xv.w * w3.z; acc.w += xv.w * w3.w;
            }
        }
        *(float4*)&T[(size_t)r * 64 + f0] = acc;
    } else {
        // ---- CSR build: wave per row, ballot prefix-compaction (ascending j) ----
        unsigned short* adjs = ((unsigned short*)Wl) + wave * CAP;   // 256 B per wave
        int r = blockIdx.x * 4 + wave;                 // global row in [0, B*N)
        const float4* Arow = (const float4*)(A + (size_t)r * NN);
        // issue all 4 independent loads up front (one vmcnt drain covers all)
        float4 v0 = Arow[lane];
        float4 v1 = Arow[64 + lane];
        float4 v2 = Arow[128 + lane];
        float4 v3 = Arow[192 + lane];
        int c = 0;
        unsigned long long lt = (lane == 0) ? 0ULL : ((1ULL << lane) - 1ULL);
        float4 vv[4] = {v0, v1, v2, v3};
#pragma unroll
        for (int it = 0; it < 4; ++it) {
            float4 v = vv[it];
            int j0 = it * 256 + lane * 4;
            unsigned long long m0 = __ballot(v.x != 0.f);
            unsigned long long m1 = __ballot(v.y != 0.f);
            unsigned long long m2 = __ballot(v.z != 0.f);
            unsigned long long m3 = __ballot(v.w != 0.f);
            int before = __popcll(m0 & lt) + __popcll(m1 & lt) +
                         __popcll(m2 & lt) + __popcll(m3 & lt);
            int p = c + before;
            if (v.x != 0.f) { if (p < CAP) adjs[p] = (unsigned short)(j0 + 0); ++p; }
            if (v.y != 0.f) { if (p < CAP) adjs[p] = (unsigned short)(j0 + 1); ++p; }
            if (v.z != 0.f) { if (p < CAP) adjs[p] = (unsigned short)(j0 + 2); ++p; }
            if (v.w != 0.f) { if (p < CAP) adjs[p] = (unsigned short)(j0 + 3); ++p; }
            c += __popcll(m0) + __popcll(m1) + __popcll(m2) + __popcll(m3);
        }
        int cc = (c > CAP) ? CAP : c;
        // coalesced flush: one u32 per lane covers 2 entries
        uint32_t* dst = (uint32_t*)(adj + (size_t)r * CAP);
        if (lane * 2 < cc) dst[lane] = ((const uint32_t*)adjs)[lane];
        if (lane == 0) {
            cnt[r] = cc;
            float D = 1.0f / sqrtf((float)c + 1.0f + EPSV);
            c1[r] = D;
            c2[r] = D * D;
        }
    }
}

// ---------------- fused mid: [0,8192) = deg, [8192,10240) = gemm64 (scaled) ----------------
// W in 16 KB static LDS; deg blocks first (latency-bound part starts at t=0).
__global__ __launch_bounds__(256) void k_mid(const unsigned short* __restrict__ adj,
                                             const int* __restrict__ cnt,
                                             const float* __restrict__ nm,
                                             float* __restrict__ c1, float* __restrict__ c2,
                                             const float* __restrict__ Xin,
                                             const float* __restrict__ W,
                                             const float* __restrict__ y,
                                             float* __restrict__ T) {
    __shared__ __align__(16) float Wl[64 * 64];    // 16 KB
    int tid = threadIdx.x;
    if (blockIdx.x >= 8192) {
        // ---- gemm64 with tanh(y)*nm row-scale ----
        int gid = blockIdx.x - 8192;
        int b = gid & 31;                   // XCD matches spmm reader
        int cch = gid >> 5;
        int row0 = (b << 10) + cch * 16;
        for (int t = tid; t < 64 * 16; t += 256)
            ((float4*)Wl)[t] = ((const float4*)W)[t];
        __syncthreads();
        int wave = tid >> 6, lane = tid & 63;
        int rsub = lane >> 4, f0 = (lane & 15) * 4;
        int r = row0 + wave * 4 + rsub;
        float sc = tanhf(y[r]) * nm[r];     // same value across the 16-lane group
        const float4* xr = (const float4*)(Xin + (size_t)r * 64);
        float4 acc = {0.f, 0.f, 0.f, 0.f};
#pragma unroll 4
        for (int k4 = 0; k4 < 16; ++k4) {
            float4 xv = xr[k4];
            float4 w0 = *(const float4*)&Wl[(k4 * 4 + 0) * 64 + f0];
            float4 w1 = *(const float4*)&Wl[(k4 * 4 + 1) * 64 + f0];
            float4 w2 = *(const float4*)&Wl[(k4 * 4 + 2) * 64 + f0];
            float4 w3 = *(const float4*)&Wl[(k4 * 4 + 3) * 64 + f0];
            acc.x += xv.x * w0.x; acc.y += xv.x * w0.y; acc.z += xv.x * w0.z; acc.w += xv.x * w0.w;
            acc.x += xv.y * w1.x; acc.y += xv.y * w1.y; acc.z += xv.y * w1.z; acc.w += xv.y * w1.w;
            acc.x += xv.z * w2.x; acc.y += xv.z * w2.y; acc.z += xv.z * w2.z; acc.w += xv.z * w2.w;
            acc.x += xv.w * w3.x; acc.y += xv.w * w3.y; acc.z += xv.w * w3.z; acc.w += xv.w * w3.w;
        }
        acc.x *= sc; acc.y *= sc; acc.z *= sc; acc.w *= sc;
        *(float4*)&T[(size_t)r * 64 + f0] = acc;
    } else {
        // ---- masked degree, wave per row (nm entries are 0/1 -> order-exact) ----
        int wave = tid >> 6, lane = tid & 63;
        int r = blockIdx.x * 4 + wave;
        int b = r >> 10;
        const unsigned short* arow = adj + (size_t)r * CAP;
        const float* nmb = nm + (b << 10);
        int n = cnt[r];
        float s = 0.f;
        if (lane < n)      s  = nmb[arow[lane]];
        if (lane + 64 < n) s += nmb[arow[lane + 64]];
        for (int sh = 32; sh; sh >>= 1) s += __shfl_xor(s, sh, 64);
        if (lane == 0) {
            float m = nm[r];
            float D = 1.0f / sqrtf(m * s + 1.0f + EPSV);
            c1[r] = m * D;
            c2[r] = D * D;
        }
    }
}

// ---------------- SpMM + self + bias + relu (+ pool score OR fused global max) ----------------
// 2048 blocks, 16 rows/block (wave does 4 sequential rows) -> c1s staging amortized 4x.
// XCD swizzle: blockIdx = cch*32 + b keeps graph b's T gathers on XCD b%8's L2.
__global__ __launch_bounds__(256) void k_spmm(const unsigned short* __restrict__ adj,
                                              const int* __restrict__ cnt,
                                              const float* __restrict__ c1,
                                              const float* __restrict__ c2,
                                              const float* __restrict__ T,
                                              const float* __restrict__ bias,
                                              float* __restrict__ X,
                                              const float* __restrict__ p,
                                              float* __restrict__ y,
                                              float* __restrict__ gmax) {
    __shared__ __align__(16) float c1s[NN];
    __shared__ float red[4][64];
    int b   = blockIdx.x & 31;            // graph
    int cch = blockIdx.x >> 5;            // chunk in [0,64)
    int tid = threadIdx.x;
    ((float4*)c1s)[tid] = ((const float4*)(c1 + (b << 10)))[tid];
    __syncthreads();
    int wave = tid >> 6, lane = tid & 63;
    int r0 = (b << 10) + cch * 16 + wave * 4;
    const float* Tb = T + ((size_t)(b << 10) << 6);
    float bv = bias[lane];
    float pv = 0.f, ppinv = 0.f;
    if (p != nullptr) {
        pv = p[lane];
        float pp = pv * pv;
        for (int s = 32; s; s >>= 1) pp += __shfl_xor(pp, s, 64);
        ppinv = 1.0f / sqrtf(pp);
    }
    float vmax = 0.f;
#pragma unroll
    for (int rr = 0; rr < 4; ++rr) {
        int r = r0 + rr;
        const unsigned short* arow = adj + (size_t)r * CAP;
        int n = cnt[r];
        float acc0 = 0.f, acc1 = 0.f, acc2 = 0.f, acc3 = 0.f;
        int t = 0;
        for (; t + 4 <= n; t += 4) {
            ushort4 j4 = *(const ushort4*)(arow + t);
            acc0 += c1s[j4.x] * Tb[((int)j4.x << 6) + lane];
            acc1 += c1s[j4.y] * Tb[((int)j4.y << 6) + lane];
            acc2 += c1s[j4.z] * Tb[((int)j4.z << 6) + lane];
            acc3 += c1s[j4.w] * Tb[((int)j4.w << 6) + lane];
        }
        for (; t < n; ++t) {
            int j = arow[t];
            acc0 += c1s[j] * Tb[(j << 6) + lane];
        }
        float acc = (acc0 + acc1) + (acc2 + acc3);
        int rl = r & 1023;
        float o = c1s[rl] * acc + c2[r] * T[((size_t)r << 6) + lane] + bv;
        o = fmaxf(o, 0.f);
        if (X != nullptr) X[((size_t)r << 6) + lane] = o;
        if (p != nullptr) {
            float a = o * pv;
            for (int s = 32; s; s >>= 1) a += __shfl_xor(a, s, 64);
            if (lane == 0) y[r] = a * ppinv;
        }
        vmax = fmaxf(vmax, o);
    }
    if (gmax != nullptr) {
        red[wave][lane] = vmax;
        __syncthreads();
        if (wave == 0) {
            float m = fmaxf(fmaxf(red[0][lane], red[1][lane]),
                            fmaxf(red[2][lane], red[3][lane]));
            // all values >= 0: int compare of float bits preserves order; gmax pre-zeroed
            atomicMax((int*)&gmax[(b << 6) + lane], __float_as_int(m));
        }
    }
}

// ---------------- pool ranking: stable-argsort semantics, 16 blocks/graph ----------------
__global__ __launch_bounds__(256) void k_rank(const float* __restrict__ y,
                                              const float* __restrict__ maskSrc,
                                              const int* __restrict__ nsrc,
                                              float* __restrict__ nmOut,
                                              int* __restrict__ ncur) {
    __shared__ __align__(16) float yv[NN];
    int b = blockIdx.x >> 4;       // 16 blocks per graph
    int sub = blockIdx.x & 15;
    int tid = threadIdx.x;
    const float INF = __builtin_inff();
    {
        float4 v = ((const float4*)(y + (b << 10)))[tid];
        float4 m = ((const float4*)(maskSrc + (b << 10)))[tid];
        v.x = (m.x > 0.f) ? v.x : INF;
        v.y = (m.y > 0.f) ? v.y : INF;
        v.z = (m.z > 0.f) ? v.z : INF;
        v.w = (m.w > 0.f) ? v.w : INF;
        ((float4*)yv)[tid] = v;
    }
    int n = nsrc[b];
    const float RM = (float)(1.0 - 0.8);   // 0.2f, matches jax f32 semantics
    int nrem = (int)((float)n * RM);
    if (sub == 0 && tid == 0) ncur[b] = n - nrem;
    __syncthreads();
    int i = (sub << 6) + (tid >> 2);       // 64 nodes per block, 4 threads per node
    int q = tid & 3;                       // quarter of the j-range
    float yi = yv[i];
    int rank = 0;
    if (yi < INF) {
        const float4* jbase = (const float4*)yv + (q << 6);
        int j0 = q << 8;
#pragma unroll 8
        for (int t = 0; t < 64; ++t) {
            float4 a = jbase[t];
            int j = j0 + t * 4;
            rank += (a.x < yi || (a.x == yi && j     < i)) ? 1 : 0;
            rank += (a.y < yi || (a.y == yi && j + 1 < i)) ? 1 : 0;
            rank += (a.z < yi || (a.z == yi && j + 2 < i)) ? 1 : 0;
            rank += (a.w < yi || (a.w == yi && j + 3 < i)) ? 1 : 0;
        }
    }
    rank += __shfl_xor(rank, 1, 64);
    rank += __shfl_xor(rank, 2, 64);
    if (q == 0) {
        float nmv = (yi < INF && rank >= nrem) ? 1.f : 0.f;
        nmOut[(b << 10) + i] = nmv;
    }
}

// ---------------- final fc from the fused global-max buffer ----------------
__global__ __launch_bounds__(64) void k_fc(const float* __restrict__ gmax,
                                           const float* __restrict__ Wfc,
                                           const float* __restrict__ bfc,
                                           float* __restrict__ out) {
    __shared__ float gl[64];
    int b = blockIdx.x, lane = threadIdx.x;
    gl[lane] = gmax[(b << 6) + lane];
    __syncthreads();
    if (lane < NOUT) {
        float acc = bfc[lane];
        for (int k = 0; k < 64; ++k) acc += gl[k] * Wfc[k * NOUT + lane];
        out[b * NOUT + lane] = acc;
    }
}

extern "C" void kernel_launch(void* const* d_in, const int* in_sizes, int n_in,
                              void* d_out, int out_size, void* d_ws, size_t ws_size,
                              hipStream_t stream) {
    const float* x    = (const float*)d_in[0];
    const float* A    = (const float*)d_in[1];
    const float* mask = (const float*)d_in[2];
    const int*   Nn   = (const int*)d_in[3];
    const float* W0   = (const float*)d_in[4];
    const float* b0   = (const float*)d_in[5];
    const float* W1   = (const float*)d_in[6];
    const float* b1   = (const float*)d_in[7];
    const float* W2   = (const float*)d_in[8];
    const float* b2   = (const float*)d_in[9];
    const float* p0   = (const float*)d_in[10];
    const float* p1   = (const float*)d_in[11];
    const float* Wfc  = (const float*)d_in[12];
    const float* bfc  = (const float*)d_in[13];
    float* out = (float*)d_out;

    char* ws = (char*)d_ws;
    size_t off = 0;
    auto alloc = [&](size_t bytes) -> void* {
        void* p = ws + off;
        off = (off + bytes + 255) & ~(size_t)255;
        return p;
    };
    unsigned short* adj = (unsigned short*)alloc((size_t)BB * NN * CAP * 2);
    int*   cnt  = (int*)  alloc((size_t)BB * NN * 4);
    float* X    = (float*)alloc((size_t)BB * NN * 64 * 4);
    float* T    = (float*)alloc((size_t)BB * NN * 64 * 4);
    float* c1   = (float*)alloc((size_t)BB * NN * 4);
    float* c2   = (float*)alloc((size_t)BB * NN * 4);
    float* y    = (float*)alloc((size_t)BB * NN * 4);
    float* nm0  = (float*)alloc((size_t)BB * NN * 4);
    float* nm1  = (float*)alloc((size_t)BB * NN * 4);
    int*   nc0  = (int*)  alloc((size_t)BB * 4);
    int*   nc1  = (int*)  alloc((size_t)BB * 4);
    float* gmax = (float*)alloc((size_t)BB * 64 * 4);

    // zero the fused-max buffer (ws is poisoned 0xAA before every call)
    hipMemsetAsync(gmax, 0, (size_t)BB * 64 * 4, stream);
    // 1) fused: CSR build (8192 blocks) + x@W0 gemm (2048 blocks, 2x16KB W chunks)
    k_front<<<8192 + 2048, 256, 0, stream>>>(A, x, W0, adj, cnt, c1, c2, T);
    // 2) layer 1 SpMM (+ pool-1 score)
    k_spmm<<<2048, 256, 0, stream>>>(adj, cnt, c1, c2, T, b0, X, p0, y, nullptr);
    // pool 1
    k_rank<<<BB * 16, 256, 0, stream>>>(y, mask, Nn, nm0, nc0);
    // 3) layer 2: fused deg (first) + gemm64
    k_mid<<<8192 + 2048, 256, 0, stream>>>(adj, cnt, nm0, c1, c2, X, W1, y, T);
    k_spmm<<<2048, 256, 0, stream>>>(adj, cnt, c1, c2, T, b1, X, p1, y, nullptr);
    // pool 2 (double-buffered mask)
    k_rank<<<BB * 16, 256, 0, stream>>>(y, nm0, nc0, nm1, nc1);
    // 4) layer 3: fused deg (first) + gemm64; spmm fuses global max (no X write)
    k_mid<<<8192 + 2048, 256, 0, stream>>>(adj, cnt, nm1, c1, c2, X, W2, y, T);
    k_spmm<<<2048, 256, 0, stream>>>(adj, cnt, c1, c2, T, b2, nullptr, nullptr, nullptr, gmax);
    // 5) fc from gmax
    k_fc<<<BB, 64, 0, stream>>>(gmax, Wfc, bfc, out);
}